// Round 18
// baseline (309.291 us; speedup 1.0000x reference)
//
#include <hip/hip_runtime.h>

#define NEGV (-1e9f)

typedef float vf4 __attribute__((ext_vector_type(4)));   // native vec for NT store

constexpr int BN   = 64;
constexpr int S1   = 257;
constexpr int LEN  = 32;
constexpr int CH   = S1 * S1;          // 66049
constexpr int ROWS = LEN + 1;          // 33
constexpr int ABSZ = BN * ROWS * S1;   // 542784
constexpr int EQP  = 260;              // padded row stride (16B-aligned rows)
constexpr int EQC  = S1 * EQP;         // 66820 per channel

// d_out layout (floats), reference return order: M, ll, a, b, ls, p, t
constexpr int OFF_M  = 0;
constexpr int OFF_LL = 64;
constexpr int OFF_A  = OFF_LL + ABSZ;
constexpr int OFF_B  = OFF_A + ABSZ;
constexpr int OFF_LS = OFF_B + ABSZ;
constexpr int OFF_P  = OFF_LS + 64;
constexpr int OFF_T  = OFF_P + ABSZ;   // 2171264 (mult of 4 -> 16B aligned)

// workspace layout (floats)
constexpr int WS_CS  = 0;              // fp32 cs, 64*771
constexpr int WS_M   = 64 * 771;       // +64
constexpr int WS_SCR = WS_M + 64;      // 49408 (16B aligned)

// scratch-relative offsets (floats); scratch = ws+WS_SCR if it fits, else out+OFF_T
constexpr int SC_CSD = 0;                      // fp64 cs: 64*771 doubles
constexpr int SC_EQ  = 2 * 64 * 771;
constexpr int SC_EQT = SC_EQ + 3 * EQC;
constexpr int SC_END = SC_EQT + 3 * EQC;       // ~2 MB

// ---------------------------------------------------------------- fp64 helpers
__device__ __forceinline__ double dexp(double x) {      // |x| < ~600
  double t = x * 1.4426950408889634;                    // log2(e)
  double n = floor(t);
  float  f = (float)(t - n);                            // [0,1)
  double r = (double)exp2f(f);                          // [1,2)
  long long bb = __double_as_longlong(r);
  bb += ((long long)n) << 52;                           // scale by 2^n
  return __longlong_as_double(bb);
}
__device__ __forceinline__ float dlogf(double x) {      // log(x), NEGV for <=0/tiny
  if (!(x > 1e-300)) return NEGV;
  long long bb = __double_as_longlong(x);
  int e = (int)((bb >> 52) & 0x7ff) - 1023;
  bb = (bb & 0xFFFFFFFFFFFFFLL) | 0x3FF0000000000000LL;
  float m = (float)__longlong_as_double(bb);
  return __logf(m) + (float)e * 0.69314718055994531f;
}

// raw barrier: orders LDS (lgkmcnt) but does NOT drain vmcnt.
__device__ __forceinline__ void barL() {
  asm volatile("s_waitcnt lgkmcnt(0)" ::: "memory");
  __builtin_amdgcn_s_barrier();
  __builtin_amdgcn_sched_barrier(0);
}

// ---------------------------------------------------------------- pre:
// blocks [0,771): EQ rows (masked exp, coalesced). blocks [771,822): EQT in
// 16-column chunks. blocks [822,886): per-batch log_softmax + prefix sums.
__global__ __launch_bounds__(256) void k_pre(const float* __restrict__ logits,
                                             const float* __restrict__ Q,
                                             const int* __restrict__ ls,
                                             float* __restrict__ ws,
                                             float* __restrict__ scr,
                                             float* __restrict__ out) {
  const int blk = blockIdx.x;
  const int tid = threadIdx.x;
  if (blk < 3 * S1) {
    const int c = blk / S1, i = blk - c * S1;
    float* EQ = scr + SC_EQ;
    const float* Qr = Q + c * CH + i * S1;
    for (int j = tid; j < S1; j += 256) {
      float e = __expf(Qr[j]);
      EQ[c * EQC + i * EQP + j] = ((i < j) || (i == 256)) ? e : 0.f;
    }
    return;
  }
  if (blk < 3 * S1 + 51) {
    const int g = blk - 3 * S1;          // 0..50
    const int c = g / 17, grp = g - c * 17;
    const int i = grp * 16 + (tid & 15);
    float* EQT = scr + SC_EQT;
    if (i < S1) {
      const float* Qci = Q + c * CH + i * S1;
      for (int j = tid >> 4; j < S1; j += 16) {
        float e = __expf(Qci[j]);
        EQT[c * EQC + j * EQP + i] = ((j > i) || (j == 256)) ? e : 0.f;
      }
    }
    return;
  }
  const int b = blk - 3 * S1 - 51;
  __shared__ float sC[3][256];
  {
    float l0 = logits[(b*3+0)*256 + tid];
    float l1 = logits[(b*3+1)*256 + tid];
    float l2 = logits[(b*3+2)*256 + tid];
    float mm = fmaxf(l0, fmaxf(l1, l2));
    float lse = mm + __logf(__expf(l0-mm) + __expf(l1-mm) + __expf(l2-mm));
    sC[0][tid] = l0 - lse;
    sC[1][tid] = l1 - lse;
    sC[2][tid] = l2 - lse;
  }
  __syncthreads();
  const int w = tid >> 6, lane = tid & 63;
  double* csD = (double*)(scr + SC_CSD);
  if (w < 3) {
    float*  cs32 = ws + WS_CS + b*771 + w*257;
    double* csd  = csD + b*771 + w*257;
    if (lane == 0) { cs32[0] = 0.f; csd[0] = 0.0; }
    double carry = 0.0;
    for (int t = 0; t < 4; ++t) {
      double v = (double)sC[w][t*64 + lane];
      #pragma unroll
      for (int off = 1; off < 64; off <<= 1) {
        double o = __shfl_up(v, off);
        if (lane >= off) v += o;
      }
      double r = carry + v;
      cs32[t*64 + lane + 1] = (float)r;
      csd [t*64 + lane + 1] = r;
      carry += __shfl(v, 63);
    }
  }
  if (tid == 0) out[OFF_LS + b] = (float)ls[b];
}

// ---------------------------------------------------------------- recursion
// FUSED alpha+beta per batch: grid 64, 1024 thr = 16 waves. Waves 0..7 run
// the alpha chain, waves 8..15 the beta chain (independent serial chains ->
// 4 waves/SIMD, cross-chain latency hiding). No register tile (VGPR cap 128
// at 1024 thr): inline loads, unroll 8. ecs tables replaced by on-the-fly
// dexp in phase 2 to fit LDS (~55 KB).
__global__ __launch_bounds__(1024) void k_rec(const float* __restrict__ scr,
                                              const int* __restrict__ pattern,
                                              const int* __restrict__ ls,
                                              float* __restrict__ ws,
                                              float* __restrict__ out) {
  __shared__ double csDs[771];
  __shared__ double wA[2][258];     // alpha weight vec (parity); [*][256] = raw A[256]
  __shared__ double wB[2][258];     // beta weight vec; [*][256] = B[256]*e^{cs[256]}
  __shared__ double AD[258];        // beta raw state
  __shared__ double partA[8][260];
  __shared__ double partB[8][260];
  __shared__ float eqR[3][257];     // EQ row 256
  __shared__ float eqC[3][257];     // EQ col 256
  __shared__ int patS[LEN];
  const int tid = threadIdx.x;
  const int b = blockIdx.x;
  const float* EQ  = scr + SC_EQ;
  const float* EQT = scr + SC_EQT;
  const double* csD = (const double*)(scr + SC_CSD) + b * 771;

  if (tid < LEN) patS[tid] = pattern[tid];
  const int lsb = ls[b];
  for (int idx = tid; idx < 771; idx += 1024) {
    int c = idx / 257, j = idx - c * 257;
    csDs[idx] = csD[idx];
    eqR[c][j] = EQ[c * EQC + 256 * EQP + j];
    eqC[c][j] = EQ[c * EQC + j * EQP + 256];
  }
  float* outA = out + OFF_A + b * (ROWS * S1);
  float* outB = out + OFF_B + b * (ROWS * S1);
  const int w = tid >> 6, l = tid & 63;
  const bool isBeta = (w >= 8);
  const int wl = w & 7;
  const int k0 = wl << 5, col0 = l << 2;
  const bool act = isBeta ? (col0 < k0 + 31) : (k0 < col0 + 3);

  __syncthreads();   // csDs/eqR/eqC/patS loaded
  if (tid < S1) {
    wA[0][tid] = (tid == 0) ? 1.0 : 0.0;          // A0 * e^{-cs}: e^{-cs[0]}=1
    __builtin_nontemporal_store((tid == 0) ? 0.f : NEGV, &outA[tid]);
    AD[tid] = (tid == lsb) ? 1.0 : 0.0;
    wB[0][tid] = (tid == lsb) ? dexp(csDs[patS[LEN-1]*257 + tid]) : 0.0;
    __builtin_nontemporal_store((tid == lsb) ? 0.f : NEGV, &outB[LEN * S1 + tid]);
  }
  barL();

  int cur = 0;
  for (int s = 0; s < LEN; ++s, cur ^= 1) {
    if (!isBeta) {           // ---- alpha phase 1 (step s)
      const int c = patS[s];
      const double* wc = wA[cur];
      double a0 = 0, a1 = 0, a2 = 0, a3 = 0;
      if (act) {
        const float* bp = EQ + c * EQC + k0 * EQP + col0;
        #pragma unroll 8
        for (int kk = 0; kk < 32; ++kk) {
          float4 e = *(const float4*)(bp + kk * EQP);
          double wv = wc[k0 + kk];
          a0 += wv * (double)e.x;
          a1 += wv * (double)e.y;
          a2 += wv * (double)e.z;
          a3 += wv * (double)e.w;
        }
      }
      partA[wl][col0] = a0; partA[wl][col0+1] = a1;
      partA[wl][col0+2] = a2; partA[wl][col0+3] = a3;
      double c2 = 0;
      if (l < 32) c2 = wc[k0 + l] * (double)eqC[c][k0 + l];
      c2 += __shfl_xor(c2, 1); c2 += __shfl_xor(c2, 2);
      c2 += __shfl_xor(c2, 4); c2 += __shfl_xor(c2, 8); c2 += __shfl_xor(c2, 16);
      if (l == 0) partA[wl][256] = c2;
    } else {                 // ---- beta phase 1 (step LEN-1-s)
      const int stepb = LEN - 1 - s;
      const int c = patS[stepb];
      const double* wc = wB[cur];
      double a0 = 0, a1 = 0, a2 = 0, a3 = 0;
      if (act) {
        const float* bp = EQT + c * EQC + k0 * EQP + col0;
        #pragma unroll 8
        for (int kk = 0; kk < 32; ++kk) {
          float4 e = *(const float4*)(bp + kk * EQP);
          double wv = wc[k0 + kk];
          a0 += wv * (double)e.x;
          a1 += wv * (double)e.y;
          a2 += wv * (double)e.z;
          a3 += wv * (double)e.w;
        }
      }
      partB[wl][col0] = a0; partB[wl][col0+1] = a1;
      partB[wl][col0+2] = a2; partB[wl][col0+3] = a3;
      double r2 = 0;
      if (l < 32) r2 = AD[k0 + l] * (double)eqR[c][k0 + l];
      r2 += __shfl_xor(r2, 1); r2 += __shfl_xor(r2, 2);
      r2 += __shfl_xor(r2, 4); r2 += __shfl_xor(r2, 8); r2 += __shfl_xor(r2, 16);
      if (l == 0) partB[wl][256] = r2;
    }
    barL();
    if (tid < S1) {          // ---- alpha phase 2
      const int c = patS[s];
      const int j = tid;
      const double wA256 = wA[cur][256];
      double sum = ((partA[0][j] + partA[1][j]) + (partA[2][j] + partA[3][j]))
                 + ((partA[4][j] + partA[5][j]) + (partA[6][j] + partA[7][j]));
      double Ar = dexp(csDs[c*257 + j]) * sum + wA256 * (double)eqR[c][j];
      float lo = dlogf(Ar);
      __builtin_nontemporal_store(lo, &outA[(s + 1) * S1 + j]);
      if (s == LEN - 1) {
        if (j == lsb) { out[OFF_M + b] = lo; ws[WS_M + b] = lo; }
      } else {
        const int cn = patS[s + 1];
        wA[cur ^ 1][j] = (j < 256) ? Ar * dexp(-csDs[cn*257 + j]) : Ar;
      }
    } else if (tid >= 512 && tid < 512 + S1) {   // ---- beta phase 2
      const int stepb = LEN - 1 - s;
      const int c = patS[stepb];
      const int i = tid - 512;
      const double wB256 = wB[cur][256];
      double sum = ((partB[0][i] + partB[1][i]) + (partB[2][i] + partB[3][i]))
                 + ((partB[4][i] + partB[5][i]) + (partB[6][i] + partB[7][i]));
      double Br;
      if (i < 256) Br = dexp(-csDs[c*257 + i]) * (sum + (double)eqC[c][i] * wB256);
      else         Br = sum + (double)eqR[c][256] * AD[256];
      __builtin_nontemporal_store(dlogf(Br), &outB[stepb * S1 + i]);
      AD[i] = Br;
      if (s < LEN - 1) wB[cur ^ 1][i] = Br * dexp(csDs[patS[stepb-1]*257 + i]);
    }
    barL();
  }
}

// ---------------------------------------------------------------- ll & p
__global__ __launch_bounds__(256) void k_llp(const float* __restrict__ ws,
                                             float* __restrict__ out) {
  int idx = blockIdx.x * 256 + threadIdx.x;
  if (idx >= ABSZ) return;
  int b = idx / (ROWS * S1);
  float a = out[OFF_A + idx];
  float bb = out[OFF_B + idx];
  float ll = a + bb;
  __builtin_nontemporal_store(ll, out + OFF_LL + idx);
  __builtin_nontemporal_store(ll - ws[WS_M + b], out + OFF_P + idx);
}

// ---------------------------------------------------------------- t (541 MB)
// R16 best config: slab-reuse, NT 16B stores, 576 blocks, 32 pairs/block.
__global__ __launch_bounds__(256) void k_t(const float* __restrict__ Q,
                                           const int* __restrict__ pattern,
                                           const float* __restrict__ ws,
                                           float* __restrict__ out) {
  __shared__ float qs[32 * 257];   // Q slab (32.9 KB)
  __shared__ float c1[257], c2[257], r1[32], r2[32];
  __shared__ int Kc[3][32];
  __shared__ int nK[3];
  const int tid  = threadIdx.x;
  const int slab = blockIdx.x >> 6;          // 0..8
  const int slot = blockIdx.x & 63;          // 0..63
  if (tid == 0) {
    int n0 = 0, n1 = 0, n2 = 0;
    for (int k = 0; k < LEN; ++k) {
      int c = pattern[k];
      if (c == 0) Kc[0][n0++] = k;
      else if (c == 1) Kc[1][n1++] = k;
      else Kc[2][n2++] = k;
    }
    nK[0] = n0; nK[1] = n1; nK[2] = n2;
  }
  __syncthreads();
  int c, chunk;
  {
    const int s0 = 2 * nK[0], s1 = s0 + 2 * nK[1];
    if (slot < s0)      { c = 0; chunk = slot; }
    else if (slot < s1) { c = 1; chunk = slot - s0; }
    else                { c = 2; chunk = slot - s1; }
  }
  const int nk = nK[c];
  const int i0 = slab << 5;
  const int R  = (257 - i0 < 32) ? (257 - i0) : 32;
  for (int idx = tid; idx < R * 257; idx += 256)
    qs[idx] = Q[c * CH + i0 * 257 + idx];
  const int p0 = chunk << 5;                 // 32 pairs per chunk
  for (int pp = 0; pp < 32; ++pp) {
    const int p = p0 + pp;
    const int b = p / nk, kidx = p - b * nk;
    const int k = Kc[c][kidx];
    __syncthreads();
    const float Mb = ws[WS_M + b];
    const float* cs = ws + WS_CS + b * 771 + c * 257;
    const float* ar = out + OFF_A + (b * ROWS + k) * S1;
    const float* br = out + OFF_B + (b * ROWS + k + 1) * S1;
    for (int j = tid; j < S1; j += 256) {
      float bv = br[j], cv = cs[j];
      c1[j] = bv + cv;
      c2[j] = bv;
    }
    if (tid < R) {
      const int i = i0 + tid;
      float av = ar[i];
      r1[tid] = av - cs[i] - Mb;
      r2[tid] = av - Mb + ((i == 256) ? 0.f : NEGV);
    }
    __syncthreads();
    const int bk2 = (b << 5) + k;
    float* tb = out + OFF_T + (size_t)bk2 * CH + i0 * 257;
    const int N = R * 257;
    const int lead = (4 - ((bk2 + i0) & 3)) & 3;
    const int main4 = (N - lead) >> 2;
    const int tail = N - lead - (main4 << 2);
    if (tid < lead) {
      const int sp = tid;
      float v = (sp > i0) ? (r1[0] + c1[sp]) : (r2[0] + c2[sp]);
      __builtin_nontemporal_store(qs[sp] + v, tb + sp);
    }
    if (tid >= 8 && tid < 8 + tail) {
      const int sp = lead + (main4 << 2) + (tid - 8);
      const int ii = sp / 257, j = sp - ii * 257;
      float v = (j > i0 + ii) ? (r1[ii] + c1[j]) : (r2[ii] + c2[j]);
      __builtin_nontemporal_store(qs[sp] + v, tb + sp);
    }
    for (int v4 = tid; v4 < main4; v4 += 256) {
      const int base = lead + (v4 << 2);
      int ii = base / 257, j = base - ii * 257;
      const float* qp = qs + base;
      vf4 o;
      o.x = qp[0] + ((j > i0 + ii) ? (r1[ii] + c1[j]) : (r2[ii] + c2[j]));
      ++j; if (j == 257) { j = 0; ++ii; }
      o.y = qp[1] + ((j > i0 + ii) ? (r1[ii] + c1[j]) : (r2[ii] + c2[j]));
      ++j; if (j == 257) { j = 0; ++ii; }
      o.z = qp[2] + ((j > i0 + ii) ? (r1[ii] + c1[j]) : (r2[ii] + c2[j]));
      ++j; if (j == 257) { j = 0; ++ii; }
      o.w = qp[3] + ((j > i0 + ii) ? (r1[ii] + c1[j]) : (r2[ii] + c2[j]));
      __builtin_nontemporal_store(o, (vf4*)(tb + base));
    }
  }
}

extern "C" void kernel_launch(void* const* d_in, const int* in_sizes, int n_in,
                              void* d_out, int out_size, void* d_ws, size_t ws_size,
                              hipStream_t stream) {
  const float* logits = (const float*)d_in[0];
  const float* Q      = (const float*)d_in[1];
  const int* pattern  = (const int*)d_in[2];
  const int* ls       = (const int*)d_in[3];
  float* out = (float*)d_out;
  float* ws  = (float*)d_ws;

  const size_t need = (size_t)(WS_SCR + SC_END) * sizeof(float);
  float* scr = (ws_size >= need) ? (ws + WS_SCR) : (out + OFF_T);

  k_pre<<<3*S1 + 51 + BN, 256, 0, stream>>>(logits, Q, ls, ws, scr, out);
  k_rec<<<BN, 1024, 0, stream>>>(scr, pattern, ls, ws, out);
  k_llp<<<(ABSZ + 255)/256, 256, 0, stream>>>(ws, out);
  k_t<<<9 * 64, 256, 0, stream>>>(Q, pattern, ws, out);
}

// Round 19
// 277.675 us; speedup vs baseline: 1.1139x; 1.1139x over previous
//
#include <hip/hip_runtime.h>

#define NEGV (-1e9f)

typedef float vf4 __attribute__((ext_vector_type(4)));   // native vec for NT store

constexpr int BN   = 64;
constexpr int S1   = 257;
constexpr int LEN  = 32;
constexpr int CH   = S1 * S1;          // 66049
constexpr int ROWS = LEN + 1;          // 33
constexpr int ABSZ = BN * ROWS * S1;   // 542784
constexpr int EQP  = 260;              // padded row stride (16B-aligned rows)
constexpr int EQC  = S1 * EQP;         // 66820 per channel

// d_out layout (floats), reference return order: M, ll, a, b, ls, p, t
constexpr int OFF_M  = 0;
constexpr int OFF_LL = 64;
constexpr int OFF_A  = OFF_LL + ABSZ;
constexpr int OFF_B  = OFF_A + ABSZ;
constexpr int OFF_LS = OFF_B + ABSZ;
constexpr int OFF_P  = OFF_LS + 64;
constexpr int OFF_T  = OFF_P + ABSZ;   // 2171264 (mult of 4 -> 16B aligned)

// workspace layout (floats)
constexpr int WS_CS  = 0;              // fp32 cs, 64*771
constexpr int WS_M   = 64 * 771;       // +64
constexpr int WS_SCR = WS_M + 64;      // 49408 (16B aligned)

// scratch-relative offsets (floats); scratch = ws+WS_SCR if it fits, else out+OFF_T
constexpr int SC_CSD = 0;                      // fp64 cs: 64*771 doubles
constexpr int SC_EQ  = 2 * 64 * 771;
constexpr int SC_EQT = SC_EQ + 3 * EQC;
constexpr int SC_END = SC_EQT + 3 * EQC;       // ~2 MB

// ---------------------------------------------------------------- fp64 helpers
__device__ __forceinline__ double dexp(double x) {      // |x| < ~600
  double t = x * 1.4426950408889634;                    // log2(e)
  double n = floor(t);
  float  f = (float)(t - n);                            // [0,1)
  double r = (double)exp2f(f);                          // [1,2)
  long long bb = __double_as_longlong(r);
  bb += ((long long)n) << 52;                           // scale by 2^n
  return __longlong_as_double(bb);
}
__device__ __forceinline__ float dlogf(double x) {      // log(x), NEGV for <=0/tiny
  if (!(x > 1e-300)) return NEGV;
  long long bb = __double_as_longlong(x);
  int e = (int)((bb >> 52) & 0x7ff) - 1023;
  bb = (bb & 0xFFFFFFFFFFFFFLL) | 0x3FF0000000000000LL;
  float m = (float)__longlong_as_double(bb);
  return __logf(m) + (float)e * 0.69314718055994531f;
}

// raw barrier: orders LDS (lgkmcnt) but does NOT drain vmcnt -> global
// loads/NT stores stay in flight across the barrier.
__device__ __forceinline__ void barL() {
  asm volatile("s_waitcnt lgkmcnt(0)" ::: "memory");
  __builtin_amdgcn_s_barrier();
  __builtin_amdgcn_sched_barrier(0);
}

// ---------------------------------------------------------------- pre:
// blocks [0,771): EQ rows (masked exp, coalesced). blocks [771,822): EQT in
// 16-column chunks (64B write segments). blocks [822,886): per-batch
// log_softmax + prefix sums (fp64 master in scratch, fp32 copy in ws).
__global__ __launch_bounds__(256) void k_pre(const float* __restrict__ logits,
                                             const float* __restrict__ Q,
                                             const int* __restrict__ ls,
                                             float* __restrict__ ws,
                                             float* __restrict__ scr,
                                             float* __restrict__ out) {
  const int blk = blockIdx.x;
  const int tid = threadIdx.x;
  if (blk < 3 * S1) {
    const int c = blk / S1, i = blk - c * S1;
    float* EQ = scr + SC_EQ;
    const float* Qr = Q + c * CH + i * S1;
    for (int j = tid; j < S1; j += 256) {
      float e = __expf(Qr[j]);
      EQ[c * EQC + i * EQP + j] = ((i < j) || (i == 256)) ? e : 0.f;
    }
    return;
  }
  if (blk < 3 * S1 + 51) {
    const int g = blk - 3 * S1;          // 0..50
    const int c = g / 17, grp = g - c * 17;
    const int i = grp * 16 + (tid & 15);
    float* EQT = scr + SC_EQT;
    if (i < S1) {
      const float* Qci = Q + c * CH + i * S1;
      for (int j = tid >> 4; j < S1; j += 16) {
        float e = __expf(Qci[j]);
        EQT[c * EQC + j * EQP + i] = ((j > i) || (j == 256)) ? e : 0.f;
      }
    }
    return;
  }
  const int b = blk - 3 * S1 - 51;
  __shared__ float sC[3][256];
  {
    float l0 = logits[(b*3+0)*256 + tid];
    float l1 = logits[(b*3+1)*256 + tid];
    float l2 = logits[(b*3+2)*256 + tid];
    float mm = fmaxf(l0, fmaxf(l1, l2));
    float lse = mm + __logf(__expf(l0-mm) + __expf(l1-mm) + __expf(l2-mm));
    sC[0][tid] = l0 - lse;
    sC[1][tid] = l1 - lse;
    sC[2][tid] = l2 - lse;
  }
  __syncthreads();
  const int w = tid >> 6, lane = tid & 63;
  double* csD = (double*)(scr + SC_CSD);
  if (w < 3) {
    float*  cs32 = ws + WS_CS + b*771 + w*257;
    double* csd  = csD + b*771 + w*257;
    if (lane == 0) { cs32[0] = 0.f; csd[0] = 0.0; }
    double carry = 0.0;
    for (int t = 0; t < 4; ++t) {
      double v = (double)sC[w][t*64 + lane];
      #pragma unroll
      for (int off = 1; off < 64; off <<= 1) {
        double o = __shfl_up(v, off);
        if (lane >= off) v += o;
      }
      double r = carry + v;
      cs32[t*64 + lane + 1] = (float)r;
      csd [t*64 + lane + 1] = r;
      carry += __shfl(v, 63);
    }
  }
  if (tid == 0) out[OFF_LS + b] = (float)ls[b];
}

// ---------------------------------------------------------------- recursion
// fp64 raw linear recursion (R8/R11 structure). blocks 0..63 alpha, 64..127
// beta. 512 thr = 8 waves; wave w owns rows [32w,32w+32); lane owns 4 cols.
// Full next-step register prefetch stays in flight across lgkm-only barriers.
__global__ __launch_bounds__(512, 2) void k_rec(const float* __restrict__ scr,
                                                const int* __restrict__ pattern,
                                                const int* __restrict__ ls,
                                                float* __restrict__ ws,
                                                float* __restrict__ out) {
  __shared__ double ecsP[3][257], ecsM[3][257];
  __shared__ double wDp[2][258];    // weight vec (parity); [*][256] = raw A[256] (alpha) / wD256 (beta)
  __shared__ double AD[258];        // beta only: raw B state
  __shared__ double part[8][260];   // per-wave partials; [w][256] = col/row-256 partial
  __shared__ float eqR[3][257];     // EQ row 256
  __shared__ float eqC[3][257];     // EQ col 256
  __shared__ int patS[LEN];
  const int tid = threadIdx.x;
  const bool isBeta = (blockIdx.x >= BN);
  const int b = isBeta ? (blockIdx.x - BN) : blockIdx.x;
  const float* EQ  = scr + SC_EQ;
  const float* EQT = scr + SC_EQT;
  const double* csD = (const double*)(scr + SC_CSD) + b * 771;

  if (tid < LEN) patS[tid] = pattern[tid];
  const int lsb = ls[b];
  for (int idx = tid; idx < 771; idx += 512) {
    int c = idx / 257, j = idx - c * 257;
    double x = csD[idx];
    ecsP[c][j] = dexp(x);
    ecsM[c][j] = dexp(-x);
    eqR[c][j] = EQ[c * EQC + 256 * EQP + j];
    eqC[c][j] = EQ[c * EQC + j * EQP + 256];
  }
  float* outab = out + (isBeta ? OFF_B : OFF_A) + b * (ROWS * S1);
  const int w = tid >> 6, l = tid & 63;
  const int k0 = w << 5, col0 = l << 2;
  const bool act = isBeta ? (col0 < k0 + 31) : (k0 < col0 + 3);

  if (tid < S1) {
    if (!isBeta) {
      __builtin_nontemporal_store((tid == 0) ? 0.f : NEGV, &outab[tid]);
    } else {
      AD[tid] = (tid == lsb) ? 1.0 : 0.0;
      __builtin_nontemporal_store((tid == lsb) ? 0.f : NEGV, &outab[LEN * S1 + tid]);
    }
  }
  __syncthreads();   // ecs/eqR/eqC/patS/AD visible
  if (tid < S1) {
    if (!isBeta) wDp[0][tid] = (tid == 0) ? 1.0 : 0.0;
    else         wDp[0][tid] = (tid == lsb) ? ecsP[patS[LEN-1]][tid] : 0.0;
  }
  float4 tile[32];
  {
    const float* bp = (isBeta ? EQT : EQ) +
                      (isBeta ? patS[LEN-1] : patS[0]) * EQC + k0 * EQP + col0;
    if (act) {
      #pragma unroll
      for (int kk = 0; kk < 32; ++kk) tile[kk] = *(const float4*)(bp + kk * EQP);
    }
  }
  barL();

  int cur = 0;
  if (!isBeta) {
    for (int step = 0; step < LEN; ++step, cur ^= 1) {
      const int c = patS[step];
      const double* wc = wDp[cur];
      double a0 = 0, a1 = 0, a2 = 0, a3 = 0;
      if (act) {
        #pragma unroll
        for (int kk = 0; kk < 32; ++kk) {
          float4 e = tile[kk];
          double wv = wc[k0 + kk];
          a0 += wv * (double)e.x;
          a1 += wv * (double)e.y;
          a2 += wv * (double)e.z;
          a3 += wv * (double)e.w;
        }
        if (step + 1 < LEN) {          // prefetch next step's tile
          const float* bp = EQ + patS[step+1] * EQC + k0 * EQP + col0;
          #pragma unroll
          for (int kk = 0; kk < 32; ++kk) tile[kk] = *(const float4*)(bp + kk * EQP);
        }
      }
      part[w][col0] = a0; part[w][col0+1] = a1;
      part[w][col0+2] = a2; part[w][col0+3] = a3;
      double c2 = 0;                   // col-256 partial (LDS only)
      if (l < 32) c2 = wc[k0 + l] * (double)eqC[c][k0 + l];
      c2 += __shfl_xor(c2, 1); c2 += __shfl_xor(c2, 2);
      c2 += __shfl_xor(c2, 4); c2 += __shfl_xor(c2, 8); c2 += __shfl_xor(c2, 16);
      if (l == 0) part[w][256] = c2;
      barL();
      if (tid < S1) {
        const int j = tid;
        const double wA256 = wDp[cur][256];
        double sum = ((part[0][j] + part[1][j]) + (part[2][j] + part[3][j]))
                   + ((part[4][j] + part[5][j]) + (part[6][j] + part[7][j]));
        double Ar = ecsP[c][j] * sum + wA256 * (double)eqR[c][j];
        float lo = dlogf(Ar);
        __builtin_nontemporal_store(lo, &outab[(step + 1) * S1 + j]);
        if (step == LEN - 1) {
          if (j == lsb) { out[OFF_M + b] = lo; ws[WS_M + b] = lo; }
        } else {
          wDp[cur ^ 1][j] = (j < 256) ? Ar * ecsM[patS[step+1]][j] : Ar;
        }
      }
      barL();
    }
  } else {
    for (int ss = 0; ss < LEN; ++ss, cur ^= 1) {
      const int step = LEN - 1 - ss;
      const int c = patS[step];
      const double* wc = wDp[cur];
      double a0 = 0, a1 = 0, a2 = 0, a3 = 0;
      if (act) {
        #pragma unroll
        for (int kk = 0; kk < 32; ++kk) {
          float4 e = tile[kk];
          double wv = wc[k0 + kk];
          a0 += wv * (double)e.x;
          a1 += wv * (double)e.y;
          a2 += wv * (double)e.z;
          a3 += wv * (double)e.w;
        }
        if (ss + 1 < LEN) {
          const float* bp = EQT + patS[step-1] * EQC + k0 * EQP + col0;
          #pragma unroll
          for (int kk = 0; kk < 32; ++kk) tile[kk] = *(const float4*)(bp + kk * EQP);
        }
      }
      part[w][col0] = a0; part[w][col0+1] = a1;
      part[w][col0+2] = a2; part[w][col0+3] = a3;
      double r2 = 0;                   // row-256 output partial (LDS only)
      if (l < 32) r2 = AD[k0 + l] * (double)eqR[c][k0 + l];
      r2 += __shfl_xor(r2, 1); r2 += __shfl_xor(r2, 2);
      r2 += __shfl_xor(r2, 4); r2 += __shfl_xor(r2, 8); r2 += __shfl_xor(r2, 16);
      if (l == 0) part[w][256] = r2;
      barL();
      if (tid < S1) {
        const int i = tid;
        const double wB256 = wDp[cur][256];
        double sum = ((part[0][i] + part[1][i]) + (part[2][i] + part[3][i]))
                   + ((part[4][i] + part[5][i]) + (part[6][i] + part[7][i]));
        double Ar;
        if (i < 256) Ar = ecsM[c][i] * (sum + (double)eqC[c][i] * wB256);
        else         Ar = sum + (double)eqR[c][256] * AD[256];
        __builtin_nontemporal_store(dlogf(Ar), &outab[step * S1 + i]);
        AD[i] = Ar;
        if (ss < LEN - 1) wDp[cur ^ 1][i] = Ar * ecsP[patS[step-1]][i];
      }
      barL();
    }
  }
}

// ---------------------------------------------------------------- ll & p
__global__ __launch_bounds__(256) void k_llp(const float* __restrict__ ws,
                                             float* __restrict__ out) {
  int idx = blockIdx.x * 256 + threadIdx.x;
  if (idx >= ABSZ) return;
  int b = idx / (ROWS * S1);
  float a = out[OFF_A + idx];
  float bb = out[OFF_B + idx];
  float ll = a + bb;
  __builtin_nontemporal_store(ll, out + OFF_LL + idx);
  __builtin_nontemporal_store(ll - ws[WS_M + b], out + OFF_P + idx);
}

// ---------------------------------------------------------------- t (541 MB)
// R16 structure (slab-reuse, NT 16B stores, 576 blocks, 32 pairs/block) with
// ONE change: lgkm-only pair barriers -> NT store queue never drains inside
// the pair loop (stores stream continuously; staging overlaps store retire).
__global__ __launch_bounds__(256) void k_t(const float* __restrict__ Q,
                                           const int* __restrict__ pattern,
                                           const float* __restrict__ ws,
                                           float* __restrict__ out) {
  __shared__ float qs[32 * 257];   // Q slab (32.9 KB)
  __shared__ float c1[257], c2[257], r1[32], r2[32];
  __shared__ int Kc[3][32];
  __shared__ int nK[3];
  const int tid  = threadIdx.x;
  const int slab = blockIdx.x >> 6;          // 0..8
  const int slot = blockIdx.x & 63;          // 0..63
  if (tid == 0) {
    int n0 = 0, n1 = 0, n2 = 0;
    for (int k = 0; k < LEN; ++k) {
      int c = pattern[k];
      if (c == 0) Kc[0][n0++] = k;
      else if (c == 1) Kc[1][n1++] = k;
      else Kc[2][n2++] = k;
    }
    nK[0] = n0; nK[1] = n1; nK[2] = n2;
  }
  __syncthreads();
  // chunk-slot -> (c, chunk); channel c owns 2*nK[c] slots (sum = 64)
  int c, chunk;
  {
    const int s0 = 2 * nK[0], s1 = s0 + 2 * nK[1];
    if (slot < s0)      { c = 0; chunk = slot; }
    else if (slot < s1) { c = 1; chunk = slot - s0; }
    else                { c = 2; chunk = slot - s1; }
  }
  const int nk = nK[c];
  const int i0 = slab << 5;
  const int R  = (257 - i0 < 32) ? (257 - i0) : 32;
  for (int idx = tid; idx < R * 257; idx += 256)
    qs[idx] = Q[c * CH + i0 * 257 + idx];    // contiguous, coalesced
  const int p0 = chunk << 5;                 // 32 pairs per chunk
  for (int pp = 0; pp < 32; ++pp) {
    const int p = p0 + pp;                   // < 64*nk by construction
    const int b = p / nk, kidx = p - b * nk;
    const int k = Kc[c][kidx];
    barL();                                  // prev readers done (LDS only; stores stay in flight)
    const float Mb = ws[WS_M + b];
    const float* cs = ws + WS_CS + b * 771 + c * 257;
    const float* ar = out + OFF_A + (b * ROWS + k) * S1;
    const float* br = out + OFF_B + (b * ROWS + k + 1) * S1;
    for (int j = tid; j < S1; j += 256) {
      float bv = br[j], cv = cs[j];
      c1[j] = bv + cv;
      c2[j] = bv;
    }
    if (tid < R) {
      const int i = i0 + tid;
      float av = ar[i];
      r1[tid] = av - cs[i] - Mb;                         // j > i
      r2[tid] = av - Mb + ((i == 256) ? 0.f : NEGV);     // row 256 / NEG
    }
    barL();                                  // stage visible (LDS only)
    const int bk2 = (b << 5) + k;
    float* tb = out + OFF_T + (size_t)bk2 * CH + i0 * 257;
    const int N = R * 257;
    const int lead = (4 - ((bk2 + i0) & 3)) & 3;   // (bk2*CH + i0*257) % 4
    const int main4 = (N - lead) >> 2;
    const int tail = N - lead - (main4 << 2);
    if (tid < lead) {                              // scalar head (ii = 0)
      const int sp = tid;
      float v = (sp > i0) ? (r1[0] + c1[sp]) : (r2[0] + c2[sp]);
      __builtin_nontemporal_store(qs[sp] + v, tb + sp);
    }
    if (tid >= 8 && tid < 8 + tail) {              // scalar tail
      const int sp = lead + (main4 << 2) + (tid - 8);
      const int ii = sp / 257, j = sp - ii * 257;
      float v = (j > i0 + ii) ? (r1[ii] + c1[j]) : (r2[ii] + c2[j]);
      __builtin_nontemporal_store(qs[sp] + v, tb + sp);
    }
    for (int v4 = tid; v4 < main4; v4 += 256) {
      const int base = lead + (v4 << 2);
      int ii = base / 257, j = base - ii * 257;
      const float* qp = qs + base;
      vf4 o;
      o.x = qp[0] + ((j > i0 + ii) ? (r1[ii] + c1[j]) : (r2[ii] + c2[j]));
      ++j; if (j == 257) { j = 0; ++ii; }
      o.y = qp[1] + ((j > i0 + ii) ? (r1[ii] + c1[j]) : (r2[ii] + c2[j]));
      ++j; if (j == 257) { j = 0; ++ii; }
      o.z = qp[2] + ((j > i0 + ii) ? (r1[ii] + c1[j]) : (r2[ii] + c2[j]));
      ++j; if (j == 257) { j = 0; ++ii; }
      o.w = qp[3] + ((j > i0 + ii) ? (r1[ii] + c1[j]) : (r2[ii] + c2[j]));
      __builtin_nontemporal_store(o, (vf4*)(tb + base));   // streaming 16B
    }
  }
}

extern "C" void kernel_launch(void* const* d_in, const int* in_sizes, int n_in,
                              void* d_out, int out_size, void* d_ws, size_t ws_size,
                              hipStream_t stream) {
  const float* logits = (const float*)d_in[0];
  const float* Q      = (const float*)d_in[1];
  const int* pattern  = (const int*)d_in[2];
  const int* ls       = (const int*)d_in[3];
  float* out = (float*)d_out;
  float* ws  = (float*)d_ws;

  const size_t need = (size_t)(WS_SCR + SC_END) * sizeof(float);
  float* scr = (ws_size >= need) ? (ws + WS_SCR) : (out + OFF_T);

  k_pre<<<3*S1 + 51 + BN, 256, 0, stream>>>(logits, Q, ls, ws, scr, out);
  k_rec<<<2*BN, 512, 0, stream>>>(scr, pattern, ls, ws, out);
  k_llp<<<(ABSZ + 255)/256, 256, 0, stream>>>(ws, out);
  k_t<<<9 * 64, 256, 0, stream>>>(Q, pattern, ws, out);
}